// Round 1
// baseline (697.504 us; speedup 1.0000x reference)
//
#include <hip/hip_runtime.h>

#define NUM_NODES 1000000
#define NUM_EDGES 262144
#define NFC 9
#define CARD 50000
#define EMB 128
#define EDGE_DIM 27

// ---------------------------------------------------------------------------
// Prep kernel: fold msg-path weights.
//   w2[j] = sum_k out_w[k] * edge_w[k,j]      (j in [0,27))
//   b2    = sum_k edge_b[k] * out_w[k] + out_b
// Stored in d_ws: ws[0..26] = w2, ws[27] = b2.
// ---------------------------------------------------------------------------
__global__ void prep_kernel(const float* __restrict__ edge_w,
                            const float* __restrict__ edge_b,
                            const float* __restrict__ out_w,
                            const float* __restrict__ out_b,
                            float* __restrict__ ws) {
    int j = threadIdx.x;
    if (j < EDGE_DIM) {
        float s = 0.f;
        for (int k = 0; k < EMB; ++k) s += out_w[k] * edge_w[k * EDGE_DIM + j];
        ws[j] = s;
    } else if (j == EDGE_DIM) {
        float s = out_b[0];
        for (int k = 0; k < EMB; ++k) s += edge_b[k] * out_w[k];
        ws[EDGE_DIM] = s;
    }
}

// ---------------------------------------------------------------------------
// encode_features for one node, one wave; lane holds dims {2*lane, 2*lane+1}.
// Type t is wave-uniform -> all branches wave-uniform (no divergence).
// ---------------------------------------------------------------------------
__device__ __forceinline__ float2 encode_node(int n, int lane,
                                              const int* __restrict__ x,
                                              const float* __restrict__ emb_type,
                                              const float* __restrict__ emb_feats) {
    constexpr int TPC[NFC] = {0, 0, 0, 0, 1, 2, 2, 2, 2};
    const int* row = x + (size_t)n * 10;
    const int t = row[0];
    float2 acc = *(const float2*)(emb_type + (size_t)t * EMB + lane * 2);
#pragma unroll
    for (int h = 0; h < NFC; ++h) {
        if (TPC[h] == t) {
            const int idx = row[h + 1];
            const float2 v = *(const float2*)(emb_feats +
                                              ((size_t)h * CARD + (size_t)idx) * EMB +
                                              lane * 2);
            acc.x += v.x;
            acc.y += v.y;
        }
    }
    return acc;
}

// ---------------------------------------------------------------------------
// Main kernel: one wave per edge. 4 waves / block.
// ---------------------------------------------------------------------------
__global__ __launch_bounds__(256) void edge_pred_kernel(
    const int* __restrict__ x, const int* __restrict__ src,
    const int* __restrict__ dst, const int* __restrict__ neg_dst,
    const float* __restrict__ msg, const float* __restrict__ emb_type,
    const float* __restrict__ emb_feats, const float* __restrict__ out_w,
    const float* __restrict__ ws, float* __restrict__ out) {
    const int wave = threadIdx.x >> 6;
    const int lane = threadIdx.x & 63;
    const int e = blockIdx.x * 4 + wave;
    if (e >= NUM_EDGES) return;

    const int s = src[e];
    const int d = dst[e];
    const int nd = neg_dst[e];

    const float2 hs = encode_node(s, lane, x, emb_type, emb_feats);
    const float2 hp = encode_node(d, lane, x, emb_type, emb_feats);
    const float2 hn = encode_node(nd, lane, x, emb_type, emb_feats);

    const float2 w = *(const float2*)(out_w + lane * 2);

    const float rpx = fmaxf(hs.x + hp.x, 0.f);
    const float rpy = fmaxf(hs.y + hp.y, 0.f);
    const float rnx = fmaxf(hs.x + hn.x, 0.f);
    const float rny = fmaxf(hs.y + hn.y, 0.f);

    float pos = rpx * w.x + rpy * w.y;
    float neg = rnx * w.x + rny * w.y;

    // msg contribution (shared by pos and neg): lanes 0..26 each add one term.
    if (lane < EDGE_DIM) {
        const float m = msg[(size_t)e * EDGE_DIM + lane] * ws[lane];
        pos += m;
        neg += m;
    }

    // wave-wide reduction (64 lanes)
#pragma unroll
    for (int off = 32; off > 0; off >>= 1) {
        pos += __shfl_down(pos, off, 64);
        neg += __shfl_down(neg, off, 64);
    }

    if (lane == 0) {
        const float b2 = ws[EDGE_DIM];
        out[e] = pos + b2;
        out[NUM_EDGES + e] = neg + b2;
    }
}

extern "C" void kernel_launch(void* const* d_in, const int* in_sizes, int n_in,
                              void* d_out, int out_size, void* d_ws, size_t ws_size,
                              hipStream_t stream) {
    const int* x = (const int*)d_in[0];
    const int* src = (const int*)d_in[1];
    const int* dst = (const int*)d_in[2];
    const int* neg_dst = (const int*)d_in[3];
    const float* msg = (const float*)d_in[4];
    const float* emb_type = (const float*)d_in[5];
    const float* emb_feats = (const float*)d_in[6];
    const float* edge_w = (const float*)d_in[7];
    const float* edge_b = (const float*)d_in[8];
    const float* out_w = (const float*)d_in[9];
    const float* out_b = (const float*)d_in[10];
    float* out = (float*)d_out;
    float* ws = (float*)d_ws;

    prep_kernel<<<1, 64, 0, stream>>>(edge_w, edge_b, out_w, out_b, ws);

    const int blocks = NUM_EDGES / 4;  // 4 waves (edges) per 256-thread block
    edge_pred_kernel<<<blocks, 256, 0, stream>>>(x, src, dst, neg_dst, msg,
                                                 emb_type, emb_feats, out_w, ws,
                                                 out);
}

// Round 2
// 513.738 us; speedup vs baseline: 1.3577x; 1.3577x over previous
//
#include <hip/hip_runtime.h>

#define NUM_NODES 1000000
#define NUM_EDGES 262144
#define NFC 9
#define CARD 50000
#define EMB 128
#define EDGE_DIM 27

// ---------------------------------------------------------------------------
// Prep kernel: fold msg-path weights.
//   w2[j] = sum_k out_w[k] * edge_w[k,j]      (j in [0,27))
//   b2    = sum_k edge_b[k] * out_w[k] + out_b
// Stored in d_ws: ws[0..26] = w2, ws[27] = b2.
// ---------------------------------------------------------------------------
__global__ void prep_kernel(const float* __restrict__ edge_w,
                            const float* __restrict__ edge_b,
                            const float* __restrict__ out_w,
                            const float* __restrict__ out_b,
                            float* __restrict__ ws) {
    int j = threadIdx.x;
    if (j < EDGE_DIM) {
        float s = 0.f;
        for (int k = 0; k < EMB; ++k) s += out_w[k] * edge_w[k * EDGE_DIM + j];
        ws[j] = s;
    } else if (j == EDGE_DIM) {
        float s = out_b[0];
        for (int k = 0; k < EMB; ++k) s += edge_b[k] * out_w[k];
        ws[EDGE_DIM] = s;
    }
}

// ---------------------------------------------------------------------------
// Main kernel: one wave per edge, 4 waves/block.
// Restructured for memory-level parallelism: all 15 row-gathers issued before
// any accumulation; index ints fetched with ONE coalesced load (lanes 0..29)
// and broadcast via shuffles. All type-branches are wave-uniform & branch-free
// (padding slots alias slot 0's address -> L1 hit, weight 0).
// ---------------------------------------------------------------------------
__global__ __launch_bounds__(256) void edge_pred_kernel(
    const int* __restrict__ x, const int* __restrict__ src,
    const int* __restrict__ dst, const int* __restrict__ neg_dst,
    const float* __restrict__ msg, const float* __restrict__ emb_type,
    const float* __restrict__ emb_feats, const float* __restrict__ out_w,
    const float* __restrict__ ws, float* __restrict__ out) {
    const int wave = threadIdx.x >> 6;
    const int lane = threadIdx.x & 63;
    const int e = blockIdx.x * 4 + wave;

    const int s = src[e];
    const int d = dst[e];
    const int nd = neg_dst[e];

    // ---- msg contribution load, in flight early (independent) ----
    float mterm = 0.f;
    if (lane < EDGE_DIM) {
        mterm = msg[(size_t)e * EDGE_DIM + lane] * ws[lane];
    }

    // ---- one coalesced load for all 30 index ints (3 nodes x 10 cols) ----
    int xv = 0;
    if (lane < 30) {
        const int node = (lane < 10) ? s : (lane < 20) ? d : nd;
        xv = x[(size_t)node * 10 + (lane % 10)];
    }

    // ---- compute all addresses + issue all 15 gathers before accumulating --
    float2 v[3][5];
    float w[3][4];
#pragma unroll
    for (int n = 0; n < 3; ++n) {
        const int off = n * 10;
        const int t = __shfl(xv, off, 64);                      // wave-uniform
        const int base_h = (t == 0) ? 0 : (t == 1) ? 4 : 5;
        v[n][0] = *(const float2*)(emb_type + (size_t)t * EMB + lane * 2);
        const int i0 = __shfl(xv, off + base_h + 1, 64);
#pragma unroll
        for (int j = 0; j < 4; ++j) {
            int ij = __shfl(xv, off + base_h + 1 + j, 64);
            int hj = base_h + j;
            float wj = 1.f;
            if (t == 1 && j > 0) { ij = i0; hj = 4; wj = 0.f; } // alias slot 0
            w[n][j] = wj;
            v[n][j + 1] = *(const float2*)(emb_feats +
                                           ((size_t)hj * CARD + (size_t)ij) * EMB +
                                           lane * 2);
        }
    }

    // ---- accumulate (loads above all in flight by now) ----
    float hx[3], hy[3];
#pragma unroll
    for (int n = 0; n < 3; ++n) {
        float ax = v[n][0].x, ay = v[n][0].y;
#pragma unroll
        for (int j = 0; j < 4; ++j) {
            ax += w[n][j] * v[n][j + 1].x;
            ay += w[n][j] * v[n][j + 1].y;
        }
        hx[n] = ax; hy[n] = ay;
    }

    const float2 wv = *(const float2*)(out_w + lane * 2);

    const float rpx = fmaxf(hx[0] + hx[1], 0.f);
    const float rpy = fmaxf(hy[0] + hy[1], 0.f);
    const float rnx = fmaxf(hx[0] + hx[2], 0.f);
    const float rny = fmaxf(hy[0] + hy[2], 0.f);

    float pos = rpx * wv.x + rpy * wv.y + mterm;
    float neg = rnx * wv.x + rny * wv.y + mterm;

    // wave-wide reduction (64 lanes)
#pragma unroll
    for (int off = 32; off > 0; off >>= 1) {
        pos += __shfl_down(pos, off, 64);
        neg += __shfl_down(neg, off, 64);
    }

    if (lane == 0) {
        const float b2 = ws[EDGE_DIM];
        out[e] = pos + b2;
        out[NUM_EDGES + e] = neg + b2;
    }
}

extern "C" void kernel_launch(void* const* d_in, const int* in_sizes, int n_in,
                              void* d_out, int out_size, void* d_ws, size_t ws_size,
                              hipStream_t stream) {
    const int* x = (const int*)d_in[0];
    const int* src = (const int*)d_in[1];
    const int* dst = (const int*)d_in[2];
    const int* neg_dst = (const int*)d_in[3];
    const float* msg = (const float*)d_in[4];
    const float* emb_type = (const float*)d_in[5];
    const float* emb_feats = (const float*)d_in[6];
    const float* edge_w = (const float*)d_in[7];
    const float* edge_b = (const float*)d_in[8];
    const float* out_w = (const float*)d_in[9];
    const float* out_b = (const float*)d_in[10];
    float* out = (float*)d_out;
    float* ws = (float*)d_ws;

    prep_kernel<<<1, 64, 0, stream>>>(edge_w, edge_b, out_w, out_b, ws);

    const int blocks = NUM_EDGES / 4;  // 4 waves (edges) per 256-thread block
    edge_pred_kernel<<<blocks, 256, 0, stream>>>(x, src, dst, neg_dst, msg,
                                                 emb_type, emb_feats, out_w, ws,
                                                 out);
}

// Round 3
// 510.382 us; speedup vs baseline: 1.3666x; 1.0066x over previous
//
#include <hip/hip_runtime.h>

#define NUM_EDGES 262144
#define CARD 50000
#define EMB 128
#define EDGE_DIM 27

// ---------------------------------------------------------------------------
// Prep kernel: fold msg-path weights.
//   ws[0..26] = w2[j] = sum_k out_w[k] * edge_w[k,j]
//   ws[27]    = b2    = sum_k edge_b[k] * out_w[k] + out_b
// ---------------------------------------------------------------------------
__global__ void prep_kernel(const float* __restrict__ edge_w,
                            const float* __restrict__ edge_b,
                            const float* __restrict__ out_w,
                            const float* __restrict__ out_b,
                            float* __restrict__ ws) {
    int j = threadIdx.x;
    if (j < EDGE_DIM) {
        float s = 0.f;
        for (int k = 0; k < EMB; ++k) s += out_w[k] * edge_w[k * EDGE_DIM + j];
        ws[j] = s;
    } else if (j == EDGE_DIM) {
        float s = out_b[0];
        for (int k = 0; k < EMB; ++k) s += edge_b[k] * out_w[k];
        ws[EDGE_DIM] = s;
    }
}

// ---------------------------------------------------------------------------
// Main kernel: TWO edges per wave (6 node encodes), 4 waves/block.
//  - e0 forced wave-uniform (readfirstlane) so the whole index path
//    (src/dst/neg_dst + x rows) runs on the scalar pipe (s_load), and all
//    30 row-gather addresses are SGPR-base + shared lane*8 offset.
//  - All 30 gathers + msg issued before any accumulation (max MLP).
//  - t==1 padding loads alias the single real row (L1 hit), weight 0.
//  - Reduction: one xor-32 step per value, pack edge0->lanes 0-31 /
//    edge1->lanes 32-63, then 5 shared xor steps.
// ---------------------------------------------------------------------------
__global__ __launch_bounds__(256, 4) void edge_pred_kernel(
    const int* __restrict__ x, const int* __restrict__ src,
    const int* __restrict__ dst, const int* __restrict__ neg_dst,
    const float* __restrict__ msg, const float* __restrict__ emb_type,
    const float* __restrict__ emb_feats, const float* __restrict__ out_w,
    const float* __restrict__ ws, float* __restrict__ out) {
    const int lane = threadIdx.x & 63;
    const int wave = threadIdx.x >> 6;
    const int e0 = __builtin_amdgcn_readfirstlane(blockIdx.x * 8 + wave * 2);

    const int half = lane >> 5;  // 0 -> edge0, 1 -> edge1
    const int hl = lane & 31;

    // ---- msg term, independent, issued early ----
    float mterm = 0.f;
    if (hl < EDGE_DIM) {
        mterm = msg[(size_t)(e0 + half) * EDGE_DIM + hl] * ws[hl];
    }

    const int loff = lane * 2;

    int nodes[6];
    nodes[0] = src[e0];     nodes[1] = dst[e0];     nodes[2] = neg_dst[e0];
    nodes[3] = src[e0 + 1]; nodes[4] = dst[e0 + 1]; nodes[5] = neg_dst[e0 + 1];

    float2 v[6][5];
    float wpad[6];

#pragma unroll
    for (int n = 0; n < 6; ++n) {
        const int* xr = x + (size_t)nodes[n] * 10;
        const int t = xr[0];
        const int c1 = xr[1], c2 = xr[2], c3 = xr[3], c4 = xr[4], c5 = xr[5],
                  c6 = xr[6], c7 = xr[7], c8 = xr[8], c9 = xr[9];
        // type -> (col indices, table ids); t==1 pads alias the real row.
        const int i0 = (t == 0) ? c1 : (t == 1) ? c5 : c6;
        const int i1 = (t == 0) ? c2 : (t == 1) ? c5 : c7;
        const int i2 = (t == 0) ? c3 : (t == 1) ? c5 : c8;
        const int i3 = (t == 0) ? c4 : (t == 1) ? c5 : c9;
        const int h0 = (t == 0) ? 0 : (t == 1) ? 4 : 5;
        const int h1 = (t == 0) ? 1 : (t == 1) ? 4 : 6;
        const int h2 = (t == 0) ? 2 : (t == 1) ? 4 : 7;
        const int h3 = (t == 0) ? 3 : (t == 1) ? 4 : 8;
        wpad[n] = (t == 1) ? 0.f : 1.f;

        v[n][0] = *(const float2*)(emb_type + (size_t)t * EMB + loff);
        v[n][1] = *(const float2*)(emb_feats + ((size_t)h0 * CARD + (size_t)i0) * EMB + loff);
        v[n][2] = *(const float2*)(emb_feats + ((size_t)h1 * CARD + (size_t)i1) * EMB + loff);
        v[n][3] = *(const float2*)(emb_feats + ((size_t)h2 * CARD + (size_t)i2) * EMB + loff);
        v[n][4] = *(const float2*)(emb_feats + ((size_t)h3 * CARD + (size_t)i3) * EMB + loff);
    }

    // ---- accumulate (all loads already in flight) ----
    float hx[6], hy[6];
#pragma unroll
    for (int n = 0; n < 6; ++n) {
        const float ax = v[n][0].x + v[n][1].x;        // type row + col0 (always w=1)
        const float ay = v[n][0].y + v[n][1].y;
        const float bx = v[n][2].x + v[n][3].x + v[n][4].x;
        const float by = v[n][2].y + v[n][3].y + v[n][4].y;
        hx[n] = ax + wpad[n] * bx;
        hy[n] = ay + wpad[n] * by;
    }

    const float2 wv = *(const float2*)(out_w + loff);

    // edge0: src=0, dst=1, neg=2 ; edge1: src=3, dst=4, neg=5
    float p0 = fmaxf(hx[0] + hx[1], 0.f) * wv.x + fmaxf(hy[0] + hy[1], 0.f) * wv.y;
    float q0 = fmaxf(hx[0] + hx[2], 0.f) * wv.x + fmaxf(hy[0] + hy[2], 0.f) * wv.y;
    float p1 = fmaxf(hx[3] + hx[4], 0.f) * wv.x + fmaxf(hy[3] + hy[4], 0.f) * wv.y;
    float q1 = fmaxf(hx[3] + hx[5], 0.f) * wv.x + fmaxf(hy[3] + hy[5], 0.f) * wv.y;

    // msg folded per half (half 0 lanes carry e0's msg cols, half 1 e1's)
    if (half == 0) { p0 += mterm; q0 += mterm; }
    else           { p1 += mterm; q1 += mterm; }

    // ---- reduction: xor-32 then pack per-half, 5 shared steps ----
    p0 += __shfl_xor(p0, 32, 64);
    q0 += __shfl_xor(q0, 32, 64);
    p1 += __shfl_xor(p1, 32, 64);
    q1 += __shfl_xor(q1, 32, 64);
    float pz = half ? p1 : p0;
    float qz = half ? q1 : q0;
#pragma unroll
    for (int off = 16; off > 0; off >>= 1) {
        pz += __shfl_xor(pz, off, 64);
        qz += __shfl_xor(qz, off, 64);
    }

    if (hl == 0) {
        const float b2 = ws[EDGE_DIM];
        const int e = e0 + half;
        out[e] = pz + b2;
        out[NUM_EDGES + e] = qz + b2;
    }
}

extern "C" void kernel_launch(void* const* d_in, const int* in_sizes, int n_in,
                              void* d_out, int out_size, void* d_ws, size_t ws_size,
                              hipStream_t stream) {
    const int* x = (const int*)d_in[0];
    const int* src = (const int*)d_in[1];
    const int* dst = (const int*)d_in[2];
    const int* neg_dst = (const int*)d_in[3];
    const float* msg = (const float*)d_in[4];
    const float* emb_type = (const float*)d_in[5];
    const float* emb_feats = (const float*)d_in[6];
    const float* edge_w = (const float*)d_in[7];
    const float* edge_b = (const float*)d_in[8];
    const float* out_w = (const float*)d_in[9];
    const float* out_b = (const float*)d_in[10];
    float* out = (float*)d_out;
    float* ws = (float*)d_ws;

    prep_kernel<<<1, 64, 0, stream>>>(edge_w, edge_b, out_w, out_b, ws);

    const int blocks = NUM_EDGES / 8;  // 4 waves/block, 2 edges/wave
    edge_pred_kernel<<<blocks, 256, 0, stream>>>(x, src, dst, neg_dst, msg,
                                                 emb_type, emb_feats, out_w, ws,
                                                 out);
}

// Round 4
// 507.711 us; speedup vs baseline: 1.3738x; 1.0053x over previous
//
#include <hip/hip_runtime.h>

#define NUM_EDGES 262144
#define CARD 50000
#define EMB 128
#define EDGE_DIM 27

// ---------------------------------------------------------------------------
// Prep kernel: fold msg-path weights.
//   ws[0..26] = w2[j] = sum_k out_w[k] * edge_w[k,j]
//   ws[27]    = b2    = sum_k edge_b[k] * out_w[k] + out_b
// ---------------------------------------------------------------------------
__global__ void prep_kernel(const float* __restrict__ edge_w,
                            const float* __restrict__ edge_b,
                            const float* __restrict__ out_w,
                            const float* __restrict__ out_b,
                            float* __restrict__ ws) {
    int j = threadIdx.x;
    if (j < EDGE_DIM) {
        float s = 0.f;
        for (int k = 0; k < EMB; ++k) s += out_w[k] * edge_w[k * EDGE_DIM + j];
        ws[j] = s;
    } else if (j == EDGE_DIM) {
        float s = out_b[0];
        for (int k = 0; k < EMB; ++k) s += edge_b[k] * out_w[k];
        ws[EDGE_DIM] = s;
    }
}

// ---------------------------------------------------------------------------
// Main kernel: TWO edges per wave (6 node encodes), 4 waves/block.
//  - Wave-uniform edge id -> whole index path on the scalar pipe (s_load);
//    gather addresses are SGPR-base + shared lane*8 voffset.
//  - ALL 30 row-gathers + msg + out_w issued, then sched_barrier(0) pins
//    them before any consumer: the scheduler cannot re-serialize the gather
//    stream to save registers (R3 failure mode: VGPR_Count=32).
//  - msg is non-temporal: pure streaming, keep it out of L3 so the 230 MB
//    emb table stays resident.
//  - t==1 padding gathers alias the single real row (L1 hit), weight 0.
// ---------------------------------------------------------------------------
__global__ __launch_bounds__(256, 4) void edge_pred_kernel(
    const int* __restrict__ x, const int* __restrict__ src,
    const int* __restrict__ dst, const int* __restrict__ neg_dst,
    const float* __restrict__ msg, const float* __restrict__ emb_type,
    const float* __restrict__ emb_feats, const float* __restrict__ out_w,
    const float* __restrict__ ws, float* __restrict__ out) {
    const int lane = threadIdx.x & 63;
    const int wave = threadIdx.x >> 6;
    const int e0 = __builtin_amdgcn_readfirstlane(blockIdx.x * 8 + wave * 2);

    const int half = lane >> 5;  // 0 -> edge0, 1 -> edge1
    const int hl = lane & 31;
    const int loff = lane * 2;

    // ---- scalar index loads (s_load) ----
    int nodes[6];
    nodes[0] = src[e0];     nodes[1] = dst[e0];     nodes[2] = neg_dst[e0];
    nodes[3] = src[e0 + 1]; nodes[4] = dst[e0 + 1]; nodes[5] = neg_dst[e0 + 1];

    // ---- msg term (non-temporal, independent, issued early) ----
    float mterm = 0.f;
    if (hl < EDGE_DIM) {
        mterm = __builtin_nontemporal_load(msg + (size_t)(e0 + half) * EDGE_DIM + hl) * ws[hl];
    }

    // ---- issue ALL gathers before any accumulation ----
    float2 v[6][5];
    float wpad[6];
#pragma unroll
    for (int n = 0; n < 6; ++n) {
        const int* xr = x + (size_t)nodes[n] * 10;
        const int t = xr[0];
        const int c1 = xr[1], c2 = xr[2], c3 = xr[3], c4 = xr[4], c5 = xr[5],
                  c6 = xr[6], c7 = xr[7], c8 = xr[8], c9 = xr[9];
        const int i0 = (t == 0) ? c1 : (t == 1) ? c5 : c6;
        const int i1 = (t == 0) ? c2 : (t == 1) ? c5 : c7;
        const int i2 = (t == 0) ? c3 : (t == 1) ? c5 : c8;
        const int i3 = (t == 0) ? c4 : (t == 1) ? c5 : c9;
        const int h0 = (t == 0) ? 0 : (t == 1) ? 4 : 5;
        const int h1 = (t == 0) ? 1 : (t == 1) ? 4 : 6;
        const int h2 = (t == 0) ? 2 : (t == 1) ? 4 : 7;
        const int h3 = (t == 0) ? 3 : (t == 1) ? 4 : 8;
        wpad[n] = (t == 1) ? 0.f : 1.f;

        v[n][0] = *(const float2*)(emb_type + (size_t)t * EMB + loff);
        v[n][1] = *(const float2*)(emb_feats + ((size_t)h0 * CARD + (size_t)i0) * EMB + loff);
        v[n][2] = *(const float2*)(emb_feats + ((size_t)h1 * CARD + (size_t)i1) * EMB + loff);
        v[n][3] = *(const float2*)(emb_feats + ((size_t)h2 * CARD + (size_t)i2) * EMB + loff);
        v[n][4] = *(const float2*)(emb_feats + ((size_t)h3 * CARD + (size_t)i3) * EMB + loff);
    }
    const float2 wv = *(const float2*)(out_w + loff);

    // Nothing may cross: all 31 loads stay issued & live here.
    __builtin_amdgcn_sched_barrier(0);

    // ---- accumulate ----
    float hx[6], hy[6];
#pragma unroll
    for (int n = 0; n < 6; ++n) {
        const float ax = v[n][0].x + v[n][1].x;   // type row + col0 (always w=1)
        const float ay = v[n][0].y + v[n][1].y;
        const float bx = v[n][2].x + v[n][3].x + v[n][4].x;
        const float by = v[n][2].y + v[n][3].y + v[n][4].y;
        hx[n] = ax + wpad[n] * bx;
        hy[n] = ay + wpad[n] * by;
    }

    // edge0: src=0, dst=1, neg=2 ; edge1: src=3, dst=4, neg=5
    float p0 = fmaxf(hx[0] + hx[1], 0.f) * wv.x + fmaxf(hy[0] + hy[1], 0.f) * wv.y;
    float q0 = fmaxf(hx[0] + hx[2], 0.f) * wv.x + fmaxf(hy[0] + hy[2], 0.f) * wv.y;
    float p1 = fmaxf(hx[3] + hx[4], 0.f) * wv.x + fmaxf(hy[3] + hy[4], 0.f) * wv.y;
    float q1 = fmaxf(hx[3] + hx[5], 0.f) * wv.x + fmaxf(hy[3] + hy[5], 0.f) * wv.y;

    if (half == 0) { p0 += mterm; q0 += mterm; }
    else           { p1 += mterm; q1 += mterm; }

    // ---- reduction: xor-32, pack per-half, 5 shared steps ----
    p0 += __shfl_xor(p0, 32, 64);
    q0 += __shfl_xor(q0, 32, 64);
    p1 += __shfl_xor(p1, 32, 64);
    q1 += __shfl_xor(q1, 32, 64);
    float pz = half ? p1 : p0;
    float qz = half ? q1 : q0;
#pragma unroll
    for (int off = 16; off > 0; off >>= 1) {
        pz += __shfl_xor(pz, off, 64);
        qz += __shfl_xor(qz, off, 64);
    }

    if (hl == 0) {
        const float b2 = ws[EDGE_DIM];
        const int e = e0 + half;
        out[e] = pz + b2;
        out[NUM_EDGES + e] = qz + b2;
    }
}

extern "C" void kernel_launch(void* const* d_in, const int* in_sizes, int n_in,
                              void* d_out, int out_size, void* d_ws, size_t ws_size,
                              hipStream_t stream) {
    const int* x = (const int*)d_in[0];
    const int* src = (const int*)d_in[1];
    const int* dst = (const int*)d_in[2];
    const int* neg_dst = (const int*)d_in[3];
    const float* msg = (const float*)d_in[4];
    const float* emb_type = (const float*)d_in[5];
    const float* emb_feats = (const float*)d_in[6];
    const float* edge_w = (const float*)d_in[7];
    const float* edge_b = (const float*)d_in[8];
    const float* out_w = (const float*)d_in[9];
    const float* out_b = (const float*)d_in[10];
    float* out = (float*)d_out;
    float* ws = (float*)d_ws;

    prep_kernel<<<1, 64, 0, stream>>>(edge_w, edge_b, out_w, out_b, ws);

    const int blocks = NUM_EDGES / 8;  // 4 waves/block, 2 edges/wave
    edge_pred_kernel<<<blocks, 256, 0, stream>>>(x, src, dst, neg_dst, msg,
                                                 emb_type, emb_feats, out_w, ws,
                                                 out);
}